// Round 2
// baseline (230.297 us; speedup 1.0000x reference)
//
#include <hip/hip_runtime.h>
#include <math.h>

#define B_   128
#define T_   50
#define MI_  32
#define E_   128
#define EW_  16
#define D_   144
#define G_   432        // 3*D
#define N_   (B_*T_)    // 6400

// ---------------------------------------------------------------------------
// K1: basket embedding.  One block per (b,t) sample, 128 threads (one per E dim).
// ---------------------------------------------------------------------------
__global__ __launch_bounds__(128) void embed_kernel(
    const int* __restrict__ x,            // [N_][33]
    const float* __restrict__ encode_w,   // [100000][128]
    const float* __restrict__ wchange_w,  // [2][16]
    float* __restrict__ seq)              // [N_][144]
{
    int n = blockIdx.x;
    int tid = threadIdx.x;
    __shared__ int xi[33];
    if (tid < 33) xi[tid] = x[n * 33 + tid];
    __syncthreads();

    float acc = 0.f;
    float cnt = 0.f;
    #pragma unroll
    for (int i = 0; i < MI_; ++i) {
        int it = xi[i];
        if (it != 0) {                       // uniform branch per block
            cnt += 1.f;
            acc += encode_w[it * E_ + tid];  // coalesced 512B row
        }
    }
    seq[n * D_ + tid] = acc / fmaxf(cnt, 1.f);
    if (tid < EW_) {
        int flag = xi[32];
        seq[n * D_ + E_ + tid] = wchange_w[flag * EW_ + tid];
    }
}

// ---------------------------------------------------------------------------
// K2/K4: C[M][N] = A[M][144] * Bw[N][144]^T + bias[N].  K fixed = 144.
// 64x64 tile, k-major LDS (pad 68 words -> conflict-free b128 reads), BK=48.
// ---------------------------------------------------------------------------
#define GK   144
#define GBK  48
#define GPAD 68

__global__ __launch_bounds__(256) void gemm_bias_kernel(
    const float* __restrict__ A,
    const float* __restrict__ Bw,
    const float* __restrict__ bias,
    float* __restrict__ C,
    int M, int N)
{
    __shared__ float As[GBK * GPAD];
    __shared__ float Bs[GBK * GPAD];

    int tid = threadIdx.x;
    int row0 = blockIdx.x * 64;
    int col0 = blockIdx.y * 64;
    int tx = tid & 15;        // col group
    int ty = tid >> 4;        // row group

    float acc[4][4] = {};

    int sr = tid >> 2;
    int skq0 = tid & 3;

    for (int k0 = 0; k0 < GK; k0 += GBK) {
        __syncthreads();
        #pragma unroll
        for (int i = 0; i < 3; ++i) {
            int kq = skq0 + i * 4;          // 0..11  (48 k / 4)
            float4 a = *(const float4*)&A[(size_t)(row0 + sr) * GK + k0 + kq * 4];
            int nrow = col0 + sr;
            float4 b = make_float4(0.f, 0.f, 0.f, 0.f);
            if (nrow < N)
                b = *(const float4*)&Bw[(size_t)nrow * GK + k0 + kq * 4];
            As[(kq * 4 + 0) * GPAD + sr] = a.x;
            As[(kq * 4 + 1) * GPAD + sr] = a.y;
            As[(kq * 4 + 2) * GPAD + sr] = a.z;
            As[(kq * 4 + 3) * GPAD + sr] = a.w;
            Bs[(kq * 4 + 0) * GPAD + sr] = b.x;
            Bs[(kq * 4 + 1) * GPAD + sr] = b.y;
            Bs[(kq * 4 + 2) * GPAD + sr] = b.z;
            Bs[(kq * 4 + 3) * GPAD + sr] = b.w;
        }
        __syncthreads();

        #pragma unroll 4
        for (int k = 0; k < GBK; ++k) {
            float4 a4 = *(const float4*)&As[k * GPAD + ty * 4];
            float4 b4 = *(const float4*)&Bs[k * GPAD + tx * 4];
            float av[4] = {a4.x, a4.y, a4.z, a4.w};
            float bv[4] = {b4.x, b4.y, b4.z, b4.w};
            #pragma unroll
            for (int i = 0; i < 4; ++i)
                #pragma unroll
                for (int j = 0; j < 4; ++j)
                    acc[i][j] = fmaf(av[i], bv[j], acc[i][j]);
        }
    }

    int c = col0 + tx * 4;
    if (c < N) {
        float4 bb = *(const float4*)&bias[c];
        #pragma unroll
        for (int i = 0; i < 4; ++i) {
            int r = row0 + ty * 4 + i;
            float4 o;
            o.x = acc[i][0] + bb.x;
            o.y = acc[i][1] + bb.y;
            o.z = acc[i][2] + bb.z;
            o.w = acc[i][3] + bb.w;
            *(float4*)&C[(size_t)r * N + c] = o;
        }
    }
}

// ---------------------------------------------------------------------------
// K3: GRU.  One block per batch element.  448 threads; thread j holds w_hh row
// j in 144 VGPRs (weights-stationary).  v2: h is block-uniform, so instead of
// 36 ds_read_b128 per thread per step (LDS-BW bound, ~1940 cy/step), each lane
// loads h into 3 registers and the dot loop broadcasts h[k] via v_readlane
// (VALU pipe, SGPR result feeds v_fmac directly).  LDS traffic/step: 3 b32
// per thread instead of 576 B per thread.
// ---------------------------------------------------------------------------

// Broadcast h[k] (k = compile-time constant) from lane registers.
#define RL(k) __uint_as_float(__builtin_amdgcn_readlane(                      \
                  __float_as_uint((k) < 64 ? h0r : ((k) < 128 ? h1r : h2r)),  \
                  (k) & 63))

__global__ __launch_bounds__(448, 1) void gru_kernel(
    const float* __restrict__ gi,     // [N_][432]
    const float* __restrict__ w_hh,   // [432][144]
    const float* __restrict__ b_hh,   // [432]
    const float* __restrict__ h0,     // [128][144]
    float* __restrict__ hseq,         // [N_][144]
    float* __restrict__ hlast)        // [128][144]
{
    int b = blockIdx.x;
    int tid = threadIdx.x;
    int lane = tid & 63;

    __shared__ __align__(16) float h[D_];
    __shared__ float gh[G_];

    int jrow = (tid < G_) ? tid : (G_ - 1);
    float wr[144];
    #pragma unroll
    for (int i = 0; i < 36; ++i) {
        float4 t = *(const float4*)&w_hh[(size_t)jrow * D_ + i * 4];
        wr[4 * i + 0] = t.x;
        wr[4 * i + 1] = t.y;
        wr[4 * i + 2] = t.z;
        wr[4 * i + 3] = t.w;
    }
    float gbias = b_hh[jrow];

    if (tid < D_) h[tid] = h0[b * D_ + tid];
    __syncthreads();

    for (int t = 0; t < T_; ++t) {
        int n = b * T_ + t;
        // prefetch gi for the gate phase (hides load latency behind the dots)
        float gir = 0.f, giz = 0.f, gin = 0.f;
        if (tid < D_) {
            gir = gi[(size_t)n * G_ + tid];
            giz = gi[(size_t)n * G_ + D_ + tid];
            gin = gi[(size_t)n * G_ + 2 * D_ + tid];
        }

        // h into lane registers (every lane of every wave must hold these —
        // v_readlane ignores exec and reads by lane index).
        float h0r = h[lane];
        float h1r = h[64 + lane];
        float h2r = h[128 + (lane & 15)];   // lanes 0..15 are the readlane srcs

        float acc0 = 0.f, acc1 = 0.f, acc2 = 0.f, acc3 = 0.f;
        #pragma unroll
        for (int k = 0; k < 144; k += 4) {
            acc0 = fmaf(RL(k + 0), wr[k + 0], acc0);
            acc1 = fmaf(RL(k + 1), wr[k + 1], acc1);
            acc2 = fmaf(RL(k + 2), wr[k + 2], acc2);
            acc3 = fmaf(RL(k + 3), wr[k + 3], acc3);
        }
        if (tid < G_)
            gh[tid] = ((acc0 + acc1) + (acc2 + acc3)) + gbias;
        __syncthreads();

        if (tid < D_) {
            float r = 1.f / (1.f + __expf(-(gir + gh[tid])));
            float z = 1.f / (1.f + __expf(-(giz + gh[D_ + tid])));
            float narg = gin + r * gh[2 * D_ + tid];
            narg = fminf(fmaxf(narg, -15.f), 15.f);
            float e2 = __expf(-2.f * narg);
            float nn = (1.f - e2) / (1.f + e2);
            float hn = (1.f - z) * nn + z * h[tid];
            hseq[(size_t)n * D_ + tid] = hn;
            h[tid] = hn;
        }
        __syncthreads();
    }

    if (tid < D_) hlast[b * D_ + tid] = h[tid];
}

// ---------------------------------------------------------------------------
extern "C" void kernel_launch(void* const* d_in, const int* in_sizes, int n_in,
                              void* d_out, int out_size, void* d_ws, size_t ws_size,
                              hipStream_t stream)
{
    const int*   x         = (const int*)d_in[0];
    // d_in[1] = lengths (unused by the reference computation)
    const float* hidden    = (const float*)d_in[2];
    const float* encode_w  = (const float*)d_in[3];
    const float* wchange_w = (const float*)d_in[4];
    const float* w_ih      = (const float*)d_in[5];
    const float* w_hh      = (const float*)d_in[6];
    const float* b_ih      = (const float*)d_in[7];
    const float* b_hh      = (const float*)d_in[8];
    const float* fc_w      = (const float*)d_in[9];
    const float* fc_b      = (const float*)d_in[10];

    float* out = (float*)d_out;              // [N_][128] then [128][144]
    float* ws  = (float*)d_ws;
    float* seq  = ws;                        //   921600 floats
    float* gi   = ws + 921600;               //  2764800 floats
    float* hseq = ws + 921600 + 2764800;     //   921600 floats  (18.4 MB total)

    // K1: embedding
    embed_kernel<<<N_, 128, 0, stream>>>(x, encode_w, wchange_w, seq);

    // K2: gi = seq @ w_ih^T + b_ih   (M=6400, N=432)
    gemm_bias_kernel<<<dim3(N_ / 64, (G_ + 63) / 64), 256, 0, stream>>>(
        seq, w_ih, b_ih, gi, N_, G_);

    // K3: GRU over T=50
    gru_kernel<<<B_, 448, 0, stream>>>(gi, w_hh, b_hh, hidden, hseq,
                                       out + (size_t)N_ * E_);

    // K4: dynamic_user = hseq @ fc_w^T + fc_b   (M=6400, N=128)
    gemm_bias_kernel<<<dim3(N_ / 64, E_ / 64), 256, 0, stream>>>(
        hseq, fc_w, fc_b, out, N_, E_);
}

// Round 3
// 194.509 us; speedup vs baseline: 1.1840x; 1.1840x over previous
//
#include <hip/hip_runtime.h>
#include <math.h>

#define B_   128
#define T_   50
#define MI_  32
#define E_   128
#define EW_  16
#define D_   144
#define G_   432        // 3*D
#define N_   (B_*T_)    // 6400

// ---------------------------------------------------------------------------
// K1: basket embedding.  One block per (b,t) sample, 128 threads (one per E dim).
// ---------------------------------------------------------------------------
__global__ __launch_bounds__(128) void embed_kernel(
    const int* __restrict__ x,            // [N_][33]
    const float* __restrict__ encode_w,   // [100000][128]
    const float* __restrict__ wchange_w,  // [2][16]
    float* __restrict__ seq)              // [N_][144]
{
    int n = blockIdx.x;
    int tid = threadIdx.x;
    __shared__ int xi[33];
    if (tid < 33) xi[tid] = x[n * 33 + tid];
    __syncthreads();

    float acc = 0.f;
    float cnt = 0.f;
    #pragma unroll
    for (int i = 0; i < MI_; ++i) {
        int it = xi[i];
        if (it != 0) {                       // uniform branch per block
            cnt += 1.f;
            acc += encode_w[it * E_ + tid];  // coalesced 512B row
        }
    }
    seq[n * D_ + tid] = acc / fmaxf(cnt, 1.f);
    if (tid < EW_) {
        int flag = xi[32];
        seq[n * D_ + E_ + tid] = wchange_w[flag * EW_ + tid];
    }
}

// ---------------------------------------------------------------------------
// K2/K4: C[M][N] = A[M][144] * Bw[N][144]^T + bias[N].  K fixed = 144.
// 64x64 tile, k-major LDS (pad 68 words -> conflict-free b128 reads), BK=48.
// ---------------------------------------------------------------------------
#define GK   144
#define GBK  48
#define GPAD 68

__global__ __launch_bounds__(256) void gemm_bias_kernel(
    const float* __restrict__ A,
    const float* __restrict__ Bw,
    const float* __restrict__ bias,
    float* __restrict__ C,
    int M, int N)
{
    __shared__ float As[GBK * GPAD];
    __shared__ float Bs[GBK * GPAD];

    int tid = threadIdx.x;
    int row0 = blockIdx.x * 64;
    int col0 = blockIdx.y * 64;
    int tx = tid & 15;        // col group
    int ty = tid >> 4;        // row group

    float acc[4][4] = {};

    int sr = tid >> 2;
    int skq0 = tid & 3;

    for (int k0 = 0; k0 < GK; k0 += GBK) {
        __syncthreads();
        #pragma unroll
        for (int i = 0; i < 3; ++i) {
            int kq = skq0 + i * 4;          // 0..11  (48 k / 4)
            float4 a = *(const float4*)&A[(size_t)(row0 + sr) * GK + k0 + kq * 4];
            int nrow = col0 + sr;
            float4 b = make_float4(0.f, 0.f, 0.f, 0.f);
            if (nrow < N)
                b = *(const float4*)&Bw[(size_t)nrow * GK + k0 + kq * 4];
            As[(kq * 4 + 0) * GPAD + sr] = a.x;
            As[(kq * 4 + 1) * GPAD + sr] = a.y;
            As[(kq * 4 + 2) * GPAD + sr] = a.z;
            As[(kq * 4 + 3) * GPAD + sr] = a.w;
            Bs[(kq * 4 + 0) * GPAD + sr] = b.x;
            Bs[(kq * 4 + 1) * GPAD + sr] = b.y;
            Bs[(kq * 4 + 2) * GPAD + sr] = b.z;
            Bs[(kq * 4 + 3) * GPAD + sr] = b.w;
        }
        __syncthreads();

        #pragma unroll 4
        for (int k = 0; k < GBK; ++k) {
            float4 a4 = *(const float4*)&As[k * GPAD + ty * 4];
            float4 b4 = *(const float4*)&Bs[k * GPAD + tx * 4];
            float av[4] = {a4.x, a4.y, a4.z, a4.w};
            float bv[4] = {b4.x, b4.y, b4.z, b4.w};
            #pragma unroll
            for (int i = 0; i < 4; ++i)
                #pragma unroll
                for (int j = 0; j < 4; ++j)
                    acc[i][j] = fmaf(av[i], bv[j], acc[i][j]);
        }
    }

    int c = col0 + tx * 4;
    if (c < N) {
        float4 bb = *(const float4*)&bias[c];
        #pragma unroll
        for (int i = 0; i < 4; ++i) {
            int r = row0 + ty * 4 + i;
            float4 o;
            o.x = acc[i][0] + bb.x;
            o.y = acc[i][1] + bb.y;
            o.z = acc[i][2] + bb.z;
            o.w = acc[i][3] + bb.w;
            *(float4*)&C[(size_t)r * N + c] = o;
        }
    }
}

// ---------------------------------------------------------------------------
// K3: GRU v3.  One block per batch element, 576 threads (9 waves).
// v1 post-mortem: LDS-issue-bound (252 ds_read_b128/step x ~12cy = 3024cy/step,
// matches the measured 3542cy/step; VALUBusy 19% = the FMA issue).
// Fix: thread (g,s) g=tid>>3, s=tid&7 holds w_hh rows 6g..6g+5 for k in
// [20s,20s+20) (120 VGPRs, K zero-padded 144->160).  h-chunk read = 5
// ds_read_b128 (banks (20s+4q)%32 cover all 32 -> conflict-free).  The
// 8-lane k-reduction runs on the VALU pipe via DPP butterflies (quad_perm
// 0xB1/0x4E, row_half_mirror 0x141) -- zero LDS traffic.  LDS instrs/step:
// 252 -> ~45.
// ---------------------------------------------------------------------------
template<int CTRL>
__device__ __forceinline__ float dpp_xor_add(float x) {
    int y = __builtin_amdgcn_mov_dpp(__float_as_int(x), CTRL, 0xF, 0xF, true);
    return x + __int_as_float(y);
}

__global__ __launch_bounds__(576) void gru_kernel(
    const float* __restrict__ gi,     // [N_][432]
    const float* __restrict__ w_hh,   // [432][144]
    const float* __restrict__ b_hh,   // [432]
    const float* __restrict__ h0,     // [128][144]
    float* __restrict__ hseq,         // [N_][144]
    float* __restrict__ hlast)        // [128][144]
{
    int b = blockIdx.x;
    int tid = threadIdx.x;
    int g = tid >> 3;       // 0..71  -> rows 6g..6g+5
    int s = tid & 7;        // k-chunk [20s, 20s+20)
    int k0 = s * 20;

    __shared__ __align__(16) float h[160];   // k-padded; [144..159] stay 0
    __shared__ float gh[G_];

    // one-time: weights into VGPRs (zero-padded past k=143)
    float w[6][20];
    #pragma unroll
    for (int r = 0; r < 6; ++r) {
        const float* wrow = &w_hh[(size_t)(6 * g + r) * D_];
        #pragma unroll
        for (int q = 0; q < 5; ++q) {
            int k = k0 + 4 * q;
            float4 t = make_float4(0.f, 0.f, 0.f, 0.f);
            if (k < D_) t = *(const float4*)&wrow[k];   // k<144 -> k<=140, safe
            w[r][4 * q + 0] = t.x;
            w[r][4 * q + 1] = t.y;
            w[r][4 * q + 2] = t.z;
            w[r][4 * q + 3] = t.w;
        }
    }
    float bias = (s < 6) ? b_hh[6 * g + s] : 0.f;

    if (tid < 160) h[tid] = (tid < D_) ? h0[b * D_ + tid] : 0.f;
    __syncthreads();

    for (int t = 0; t < T_; ++t) {
        int n = b * T_ + t;
        // prefetch gi (L2-resident; overlaps the LDS reads + dot phase)
        float gir = 0.f, giz = 0.f, gin = 0.f;
        if (tid < D_) {
            gir = gi[(size_t)n * G_ + tid];
            giz = gi[(size_t)n * G_ + D_ + tid];
            gin = gi[(size_t)n * G_ + 2 * D_ + tid];
        }

        // h chunk: 5 conflict-free ds_read_b128
        float hv[20];
        #pragma unroll
        for (int q = 0; q < 5; ++q) {
            float4 t4 = *(const float4*)&h[k0 + 4 * q];
            hv[4 * q + 0] = t4.x;
            hv[4 * q + 1] = t4.y;
            hv[4 * q + 2] = t4.z;
            hv[4 * q + 3] = t4.w;
        }

        // 6 rows x 20 k partial dots (120 fmac, 6 independent chains)
        float a0 = 0.f, a1 = 0.f, a2 = 0.f, a3 = 0.f, a4 = 0.f, a5 = 0.f;
        #pragma unroll
        for (int kk = 0; kk < 20; ++kk) {
            float hk = hv[kk];
            a0 = fmaf(w[0][kk], hk, a0);
            a1 = fmaf(w[1][kk], hk, a1);
            a2 = fmaf(w[2][kk], hk, a2);
            a3 = fmaf(w[3][kk], hk, a3);
            a4 = fmaf(w[4][kk], hk, a4);
            a5 = fmaf(w[5][kk], hk, a5);
        }

        // reduce across the 8 k-chunk lanes: VALU DPP butterfly (no LDS)
        a0 = dpp_xor_add<0xB1>(a0); a0 = dpp_xor_add<0x4E>(a0); a0 = dpp_xor_add<0x141>(a0);
        a1 = dpp_xor_add<0xB1>(a1); a1 = dpp_xor_add<0x4E>(a1); a1 = dpp_xor_add<0x141>(a1);
        a2 = dpp_xor_add<0xB1>(a2); a2 = dpp_xor_add<0x4E>(a2); a2 = dpp_xor_add<0x141>(a2);
        a3 = dpp_xor_add<0xB1>(a3); a3 = dpp_xor_add<0x4E>(a3); a3 = dpp_xor_add<0x141>(a3);
        a4 = dpp_xor_add<0xB1>(a4); a4 = dpp_xor_add<0x4E>(a4); a4 = dpp_xor_add<0x141>(a4);
        a5 = dpp_xor_add<0xB1>(a5); a5 = dpp_xor_add<0x4E>(a5); a5 = dpp_xor_add<0x141>(a5);

        // lane s writes row 6g+s (s<6); all 8 lanes hold all 6 sums
        float myacc = a0;
        if (s == 1) myacc = a1;
        if (s == 2) myacc = a2;
        if (s == 3) myacc = a3;
        if (s == 4) myacc = a4;
        if (s == 5) myacc = a5;
        if (s < 6) gh[6 * g + s] = myacc + bias;
        __syncthreads();

        if (tid < D_) {
            float r = 1.f / (1.f + __expf(-(gir + gh[tid])));
            float z = 1.f / (1.f + __expf(-(giz + gh[D_ + tid])));
            float narg = gin + r * gh[2 * D_ + tid];
            narg = fminf(fmaxf(narg, -15.f), 15.f);
            float e2 = __expf(-2.f * narg);
            float nn = (1.f - e2) / (1.f + e2);
            float hn = (1.f - z) * nn + z * h[tid];
            hseq[(size_t)n * D_ + tid] = hn;
            h[tid] = hn;
        }
        __syncthreads();
    }

    if (tid < D_) hlast[b * D_ + tid] = h[tid];
}

// ---------------------------------------------------------------------------
extern "C" void kernel_launch(void* const* d_in, const int* in_sizes, int n_in,
                              void* d_out, int out_size, void* d_ws, size_t ws_size,
                              hipStream_t stream)
{
    const int*   x         = (const int*)d_in[0];
    // d_in[1] = lengths (unused by the reference computation)
    const float* hidden    = (const float*)d_in[2];
    const float* encode_w  = (const float*)d_in[3];
    const float* wchange_w = (const float*)d_in[4];
    const float* w_ih      = (const float*)d_in[5];
    const float* w_hh      = (const float*)d_in[6];
    const float* b_ih      = (const float*)d_in[7];
    const float* b_hh      = (const float*)d_in[8];
    const float* fc_w      = (const float*)d_in[9];
    const float* fc_b      = (const float*)d_in[10];

    float* out = (float*)d_out;              // [N_][128] then [128][144]
    float* ws  = (float*)d_ws;
    float* seq  = ws;                        //   921600 floats
    float* gi   = ws + 921600;               //  2764800 floats
    float* hseq = ws + 921600 + 2764800;     //   921600 floats  (18.4 MB total)

    // K1: embedding
    embed_kernel<<<N_, 128, 0, stream>>>(x, encode_w, wchange_w, seq);

    // K2: gi = seq @ w_ih^T + b_ih   (M=6400, N=432)
    gemm_bias_kernel<<<dim3(N_ / 64, (G_ + 63) / 64), 256, 0, stream>>>(
        seq, w_ih, b_ih, gi, N_, G_);

    // K3: GRU over T=50
    gru_kernel<<<B_, 576, 0, stream>>>(gi, w_hh, b_hh, hidden, hseq,
                                       out + (size_t)N_ * E_);

    // K4: dynamic_user = hseq @ fc_w^T + fc_b   (M=6400, N=128)
    gemm_bias_kernel<<<dim3(N_ / 64, E_ / 64), 256, 0, stream>>>(
        hseq, fc_w, fc_b, out, N_, E_);
}